// Round 3
// baseline (662.419 us; speedup 1.0000x reference)
//
#include <hip/hip_runtime.h>

typedef unsigned int u32;
typedef unsigned short u16;
using v4f    = __attribute__((ext_vector_type(4))) float;
using short8 = __attribute__((ext_vector_type(8))) short;

#define GAS __attribute__((address_space(1)))
#define LAS __attribute__((address_space(3)))

// ---- bf16 helpers (RNE, matches HW convert; inputs are finite) ----
__device__ __forceinline__ u16 f2bf(float f){
  u32 u = __builtin_bit_cast(u32, f);
  u32 r = (u + 0x7fffu + ((u >> 16) & 1u)) >> 16;
  return (u16)r;
}
__device__ __forceinline__ float bf2f(u16 h){
  u32 u = ((u32)h) << 16;
  return __builtin_bit_cast(float, u);
}

// async global->LDS, 16B per lane. LDS dest must be wave-uniform base + lane*16.
__device__ __forceinline__ void gld_lds16(const void* g, void* l){
  __builtin_amdgcn_global_load_lds((const GAS u32*)g, (LAS u32*)l, 16, 0, 0);
}

// ---- transpose fp32 [K][N] -> bf16 [N][K] (weights only) ----
__global__ __launch_bounds__(256) void transpose_w_bf16(
    const float* __restrict__ in, u16* __restrict__ out, int K, int N)
{
  __shared__ float t[64][65];
  const int k0 = blockIdx.x * 64, n0 = blockIdx.y * 64;
  const int tx = threadIdx.x & 63, ty = threadIdx.x >> 6;
  #pragma unroll
  for (int i = 0; i < 16; i++){
    int r = ty + i * 4;
    t[r][tx] = in[(size_t)(k0 + r) * N + (n0 + tx)];
  }
  __syncthreads();
  #pragma unroll
  for (int i = 0; i < 16; i++){
    int r = ty + i * 4;
    out[(size_t)(n0 + r) * K + (k0 + tx)] = f2bf(t[tx][r]);
  }
}

// ---- in-place softmax, one WAVE per 2048-elem row (4 rows/block) ----
__global__ __launch_bounds__(256) void softmax_rows(u16* __restrict__ S){
  const int lane = threadIdx.x & 63, wid = threadIdx.x >> 6;
  u16* p = S + ((size_t)blockIdx.x * 4 + wid) * 2048;
  uint4 u[4];
  #pragma unroll
  for (int j = 0; j < 4; j++) u[j] = ((const uint4*)p)[lane + j * 64];
  float f[32];
  #pragma unroll
  for (int j = 0; j < 4; j++){
    u32 w4[4] = {u[j].x, u[j].y, u[j].z, u[j].w};
    #pragma unroll
    for (int i = 0; i < 4; i++){
      f[j * 8 + 2*i]     = bf2f((u16)(w4[i] & 0xffffu));
      f[j * 8 + 2*i + 1] = bf2f((u16)(w4[i] >> 16));
    }
  }
  float m = f[0];
  #pragma unroll
  for (int i = 1; i < 32; i++) m = fmaxf(m, f[i]);
  #pragma unroll
  for (int o = 32; o >= 1; o >>= 1) m = fmaxf(m, __shfl_xor(m, o));
  float s = 0.f;
  #pragma unroll
  for (int i = 0; i < 32; i++){ f[i] = __expf(f[i] - m); s += f[i]; }
  #pragma unroll
  for (int o = 32; o >= 1; o >>= 1) s += __shfl_xor(s, o);
  const float inv = 1.f / s;
  #pragma unroll
  for (int j = 0; j < 4; j++){
    u32 w4[4];
    #pragma unroll
    for (int i = 0; i < 4; i++)
      w4[i] = (u32)f2bf(f[j * 8 + 2*i] * inv) |
              ((u32)f2bf(f[j * 8 + 2*i + 1] * inv) << 16);
    ((uint4*)p)[lane + j * 64] = make_uint4(w4[0], w4[1], w4[2], w4[3]);
  }
}

// ===========================================================================
// 256x256x64 bf16 GEMM, m201-style 4-phase/K-tile schedule:
//   per phase: {ds-read subtile; stage 1/4 of next tile; barrier;
//               setprio1 + 16 MFMA + setprio0; barrier}.
//   One s_waitcnt vmcnt(0) per K-tile at the top -- it targets loads issued
//   a FULL tile earlier (cheap). No sched_barrier pinning (m141).
//   512 threads = 8 waves (2M x 4N), per-wave output 128x64. 128 KiB LDS dbuf.
// LDS swizzle: linear dest; slot (r,c8) holds global k-chunk (c8 ^ (r&7));
//   reads apply the same XOR. (bank-conflict = 0, verified r1/r2)
// AMODE: 0 = A fp32 global, reg-staged (load early / cvt+ds_write late, T14)
//        1 = A bf16 via global_load_lds
//        2 = A concat(qp,x) bf16 (K split at 1024, wave-uniform select)
// EPI:   0 = +bias, bf16   1 = *scale, bf16   2 = gate-fused, fp32
//        3 = +bias, bf16 TRANSPOSED [batch][col][rowlocal]
// ===========================================================================
#define BAR() do{ asm volatile("" ::: "memory");                            \
                  __builtin_amdgcn_s_barrier();                             \
                  asm volatile("" ::: "memory"); }while(0)

#define MFMA8(B0, B1, N0, N1)                                               \
    __builtin_amdgcn_s_setprio(1);                                          \
    _Pragma("unroll")                                                       \
    for (int mi = 0; mi < 8; mi++){                                         \
      acc[mi][N0] = __builtin_amdgcn_mfma_f32_16x16x32_bf16(                \
                      a[mi], (B0), acc[mi][N0], 0, 0, 0);                   \
      acc[mi][N1] = __builtin_amdgcn_mfma_f32_16x16x32_bf16(                \
                      a[mi], (B1), acc[mi][N1], 0, 0, 0);                   \
    }                                                                       \
    __builtin_amdgcn_s_setprio(0);

template<int AMODE, int EPI>
__global__ __launch_bounds__(512) void gemm256(
    const float* __restrict__ Af,
    const u16* __restrict__ Ab,
    const u16* __restrict__ A2b,
    const u16* __restrict__ BT,
    int lda, int ldb, int K,
    void* __restrict__ Cout, int ldc,
    const float* __restrict__ bias, float scale,
    size_t aBatch, size_t bBatch, size_t cBatch,
    const u16* __restrict__ xg,
    const float* __restrict__ maskp,
    const float* __restrict__ q0p)
{
  constexpr int BK = 64;
  __shared__ __align__(16) u16 As[2][2][128 * 64];   // [buf][half][r*64 + c8*8 + e]
  __shared__ __align__(16) u16 Bs[2][2][128 * 64];

  const int z   = blockIdx.z;
  // GROUP-8 swizzle: 8 consecutive lin blocks share a B-panel, walk 8 A-panels
  const int gx   = (int)gridDim.x;
  const int lin  = (int)blockIdx.y * gx + (int)blockIdx.x;
  const int l2gx = 31 - __clz(gx);
  const int g    = lin >> (3 + l2gx);
  const int rem  = lin & ((gx << 3) - 1);
  const int m0   = ((g << 3) + (rem & 7)) * 256;
  const int n0   = (rem >> 3) * 256;

  const int tid  = (int)threadIdx.x;
  const int lane = tid & 63, wid = tid >> 6;
  const int wm   = (wid >> 2) * 128;     // A half = wid>>2
  const int wn   = (wid & 3) * 64;
  const int wnh  = wn >> 7;              // B half
  const int wnl  = wn & 127;

  const u16* Az = Ab + (size_t)z * aBatch;
  const u16* Bz = BT + (size_t)z * bBatch;

  // staging geometry: load i covers rows (tid+i*512)>>3 of a 128x64 half.
  // slot (r,c8) <- global chunk (c8 ^ (r&7))   [inverse swizzle on source]
  u32 offA[2][2], offB[2][2], ldsOff[2];
  #pragma unroll
  for (int i = 0; i < 2; i++){
    int idx = tid + i * 512;
    int r = idx >> 3, c8 = idx & 7;
    int c8s = c8 ^ (r & 7);
    #pragma unroll
    for (int h = 0; h < 2; h++){
      offA[h][i] = (u32)(((m0 + h * 128 + r) * lda + c8s * 8) * 2);
      offB[h][i] = (u32)(((n0 + h * 128 + r) * ldb + c8s * 8) * 2);
    }
    ldsOff[i] = (u32)(idx * 16);
  }

  // quarter-stage q = (h<<1)|i: AMODE!=0 -> A+B pair (2 gld); AMODE==0 -> B only
  auto stageQ = [&](int kt, int dbuf, int q){
    const int h = q >> 1, i = q & 1;
    const u32 kb = (u32)(kt * BK * 2);
    if (AMODE != 0){
      const u16* Asrc; u32 ka;
      if (AMODE == 2){
        Asrc = (kt * BK < 1024) ? Az : A2b;
        ka = (u32)(((kt * BK) & 1023) * 2);
      } else {
        Asrc = Az;
        ka = (u32)(kt * BK * 2);
      }
      gld_lds16((const char*)Asrc + offA[h][i] + ka,
                (char*)&As[dbuf][h][0] + ldsOff[i]);
    }
    gld_lds16((const char*)Bz + offB[h][i] + kb,
              (char*)&Bs[dbuf][h][0] + ldsOff[i]);
  };

  // AMODE==0: fp32 A reg-staging (T14 split: load early, cvt+ds_write late)
  v4f afr[2][2][2];
  auto loadA = [&](int kt){
    if (AMODE != 0) return;
    #pragma unroll
    for (int h = 0; h < 2; h++)
      #pragma unroll
      for (int i = 0; i < 2; i++){
        int idx = tid + i * 512;
        int r = idx >> 3, c8s = (idx & 7) ^ (r & 7);
        const float* src = Af + (size_t)(m0 + h * 128 + r) * lda + kt * BK + c8s * 8;
        afr[h][i][0] = ((const v4f*)src)[0];
        afr[h][i][1] = ((const v4f*)src)[1];
      }
  };
  auto writeA = [&](int dbuf){
    if (AMODE != 0) return;
    #pragma unroll
    for (int h = 0; h < 2; h++)
      #pragma unroll
      for (int i = 0; i < 2; i++){
        int idx = tid + i * 512;
        u32 q0 = (u32)f2bf(afr[h][i][0].x) | ((u32)f2bf(afr[h][i][0].y) << 16);
        u32 q1 = (u32)f2bf(afr[h][i][0].z) | ((u32)f2bf(afr[h][i][0].w) << 16);
        u32 q2 = (u32)f2bf(afr[h][i][1].x) | ((u32)f2bf(afr[h][i][1].y) << 16);
        u32 q3 = (u32)f2bf(afr[h][i][1].z) | ((u32)f2bf(afr[h][i][1].w) << 16);
        *(uint4*)((char*)&As[dbuf][h][0] + idx * 16) = make_uint4(q0, q1, q2, q3);
      }
  };

  v4f acc[8][4];
  #pragma unroll
  for (int mi = 0; mi < 8; mi++)
    #pragma unroll
    for (int ni = 0; ni < 4; ni++)
      acc[mi][ni] = (v4f){0.f, 0.f, 0.f, 0.f};

  // read-side swizzle: per-lane constant chunk offsets (elements)
  const int ll  = lane & 15, lq = lane >> 4;
  const int ch0 = ((0 + lq) ^ (ll & 7)) << 3;   // k 0..31
  const int ch4 = ((4 + lq) ^ (ll & 7)) << 3;   // k 32..63

  // ---- prologue: stage tile 0 into buf 0
  if (AMODE == 0){
    loadA(0);
    #pragma unroll
    for (int q = 0; q < 4; q++) stageQ(0, 0, q);
    writeA(0);           // compiler waits the fp32 loads here
  } else {
    #pragma unroll
    for (int q = 0; q < 4; q++) stageQ(0, 0, q);
  }

  const int nt = K / BK;
  for (int kt = 0; kt < nt; kt++){
    const int buf = kt & 1;
    const bool pf = (kt + 1 < nt);

    // ---- buffer-ready: tile kt's loads were issued a full tile ago.
    asm volatile("s_waitcnt vmcnt(0)" ::: "memory");
    if (AMODE == 0) asm volatile("s_waitcnt lgkmcnt(0)" ::: "memory");
    BAR();

    if (pf) loadA(kt + 1);               // fp32 A issue-early (AMODE==0)

    const u16* aB = &As[buf][wid >> 2][0] + ll * 64;
    const u16* bB = &Bs[buf][wnh][0] + (wnl + ll) * 64;

    short8 a[8], b[2];
    // ---- P1: k 0..31, ni 0..1
    b[0] = *(const short8*)(bB + ch0);
    b[1] = *(const short8*)(bB + ch0 + 1024);
    #pragma unroll
    for (int mi = 0; mi < 8; mi++) a[mi] = *(const short8*)(aB + ch0 + mi * 1024);
    if (pf) stageQ(kt + 1, buf ^ 1, 0);
    BAR();
    MFMA8(b[0], b[1], 0, 1)
    BAR();
    // ---- P2: k 0..31, ni 2..3 (reuse a)
    b[0] = *(const short8*)(bB + ch0 + 2048);
    b[1] = *(const short8*)(bB + ch0 + 3072);
    if (pf) stageQ(kt + 1, buf ^ 1, 1);
    BAR();
    MFMA8(b[0], b[1], 2, 3)
    BAR();
    // ---- P3: k 32..63, ni 0..1
    b[0] = *(const short8*)(bB + ch4);
    b[1] = *(const short8*)(bB + ch4 + 1024);
    #pragma unroll
    for (int mi = 0; mi < 8; mi++) a[mi] = *(const short8*)(aB + ch4 + mi * 1024);
    if (pf) stageQ(kt + 1, buf ^ 1, 2);
    BAR();
    MFMA8(b[0], b[1], 0, 1)
    BAR();
    // ---- P4: k 32..63, ni 2..3
    b[0] = *(const short8*)(bB + ch4 + 2048);
    b[1] = *(const short8*)(bB + ch4 + 3072);
    if (pf) stageQ(kt + 1, buf ^ 1, 3);
    BAR();
    MFMA8(b[0], b[1], 2, 3)
    BAR();

    if (pf) writeA(buf ^ 1);             // fp32 A cvt + ds_write late (AMODE==0)
  }

  // epilogue: C/D layout col = lane&15, row = (lane>>4)*4 + r (m89/m91)
  const int lr = lq * 4, lc = ll;
  if (EPI == 0 || EPI == 1){
    u16* C = (u16*)Cout + (size_t)z * cBatch;
    #pragma unroll
    for (int mi = 0; mi < 8; mi++){
      #pragma unroll
      for (int ni = 0; ni < 4; ni++){
        int col = n0 + wn + ni * 16 + lc;
        float bv = (EPI == 0) ? bias[col] : 0.f;
        #pragma unroll
        for (int r = 0; r < 4; r++){
          int row = m0 + wm + mi * 16 + lr + r;
          C[(size_t)row * ldc + col] = f2bf(acc[mi][ni][r] * scale + bv);
        }
      }
    }
  } else if (EPI == 3){
    u16* C = (u16*)Cout;
    #pragma unroll
    for (int mi = 0; mi < 8; mi++){
      int rowb = m0 + wm + mi * 16 + lr;        // multiple of 4, single batch
      int bb   = rowb >> 11;
      int rloc = rowb & 2047;
      #pragma unroll
      for (int ni = 0; ni < 4; ni++){
        int col = n0 + wn + ni * 16 + lc;
        float bv = bias[col];
        u32 pk0 = (u32)f2bf(acc[mi][ni][0] + bv) | ((u32)f2bf(acc[mi][ni][1] + bv) << 16);
        u32 pk1 = (u32)f2bf(acc[mi][ni][2] + bv) | ((u32)f2bf(acc[mi][ni][3] + bv) << 16);
        *(uint2*)&C[(size_t)bb * (1024ull * 2048) + (size_t)col * 2048 + rloc] =
            make_uint2(pk0, pk1);
      }
    }
  } else {
    float* C = (float*)Cout;
    #pragma unroll
    for (int mi = 0; mi < 8; mi++){
      #pragma unroll
      for (int ni = 0; ni < 4; ni++){
        int col = n0 + wn + ni * 16 + lc;
        float bv = bias[col];
        #pragma unroll
        for (int r = 0; r < 4; r++){
          int row = m0 + wm + mi * 16 + lr + r;
          float gg = acc[mi][ni][r] + bv;
          float sg = 1.f / (1.f + __expf(-gg));
          float xv = bf2f(xg[(size_t)row * 1024 + col]);
          C[(size_t)row * ldc + col] =
              xv * maskp[row] * sg + q0p[(size_t)row * 1024 + col];
        }
      }
    }
  }
}
#undef MFMA8
#undef BAR

// ---- 128x128x64 kernel kept for the small-workspace fallback path ----
template<int AMODE, int EPI>
__global__ __launch_bounds__(256) void gemm128(
    const float* __restrict__ Af,
    const u16* __restrict__ Ab,
    const u16* __restrict__ A2b,
    const u16* __restrict__ BT,
    int lda, int ldb, int K,
    void* __restrict__ Cout, int ldc,
    const float* __restrict__ bias, float scale,
    size_t aBatch, size_t bBatch, size_t cBatch,
    const u16* __restrict__ xg,
    const float* __restrict__ maskp,
    const float* __restrict__ q0p)
{
  constexpr int BM = 128, BN = 128, BK = 64;
  __shared__ __align__(16) u16 As[BM * BK];
  __shared__ __align__(16) u16 Bs[BN * BK];
  const int z   = blockIdx.z;
  const int lin  = blockIdx.y * gridDim.x + blockIdx.x;
  const int l2gx = 31 - __clz((int)gridDim.x);
  const int g    = lin >> (3 + l2gx);
  const int rem  = lin & (((int)gridDim.x << 3) - 1);
  const int m0   = ((g << 3) + (rem & 7)) * BM;
  const int n0   = (rem >> 3) * BN;
  const int tid = threadIdx.x;
  const int lane = tid & 63, wid = tid >> 6;
  const int wm = (wid >> 1) * 64, wn = (wid & 1) * 64;
  const u16* Abz = Ab + (size_t)z * aBatch;
  const u16* BTz = BT + (size_t)z * bBatch;

  v4f acc[4][4];
  #pragma unroll
  for (int mi = 0; mi < 4; mi++)
    #pragma unroll
    for (int ni = 0; ni < 4; ni++)
      acc[mi][ni] = (v4f){0.f, 0.f, 0.f, 0.f};

  for (int k0 = 0; k0 < K; k0 += BK){
    if (AMODE == 0){
      #pragma unroll
      for (int i = 0; i < 4; i++){
        int idx = tid + i * 256;
        int r = idx >> 3, s = idx & 7;
        const float* src = Af + (size_t)(m0 + r) * lda + (k0 + s * 8);
        v4f lo = ((const v4f*)src)[0];
        v4f hi = ((const v4f*)src)[1];
        u32 p0 = (u32)f2bf(lo.x) | ((u32)f2bf(lo.y) << 16);
        u32 p1 = (u32)f2bf(lo.z) | ((u32)f2bf(lo.w) << 16);
        u32 p2 = (u32)f2bf(hi.x) | ((u32)f2bf(hi.y) << 16);
        u32 p3 = (u32)f2bf(hi.z) | ((u32)f2bf(hi.w) << 16);
        *(uint4*)&As[(size_t)idx * 8] = make_uint4(p0, p1, p2, p3);
      }
    } else {
      #pragma unroll
      for (int i = 0; i < 4; i++){
        int idx = tid + i * 256;
        int r = idx >> 3, s = idx & 7;
        int kk = k0 + s * 8;
        const u16* src;
        if (AMODE == 2){
          src = (kk < 1024) ? (Abz + (size_t)(m0 + r) * 1024 + kk)
                            : (A2b + (size_t)(m0 + r) * 1024 + (kk - 1024));
        } else {
          src = Abz + (size_t)(m0 + r) * lda + kk;
        }
        gld_lds16(src, &As[(size_t)idx * 8]);
      }
    }
    #pragma unroll
    for (int i = 0; i < 4; i++){
      int idx = tid + i * 256;
      int r = idx >> 3, s = idx & 7;
      gld_lds16(BTz + (size_t)(n0 + r) * ldb + (k0 + s * 8), &Bs[(size_t)idx * 8]);
    }
    __syncthreads();
    #pragma unroll
    for (int ks = 0; ks < BK; ks += 32){
      short8 a[4], b[4];
      #pragma unroll
      for (int mi = 0; mi < 4; mi++)
        a[mi] = *(const short8*)&As[(wm + mi * 16 + (lane & 15)) * BK + ks + (lane >> 4) * 8];
      #pragma unroll
      for (int ni = 0; ni < 4; ni++)
        b[ni] = *(const short8*)&Bs[(wn + ni * 16 + (lane & 15)) * BK + ks + (lane >> 4) * 8];
      #pragma unroll
      for (int mi = 0; mi < 4; mi++)
        #pragma unroll
        for (int ni = 0; ni < 4; ni++)
          acc[mi][ni] = __builtin_amdgcn_mfma_f32_16x16x32_bf16(a[mi], b[ni], acc[mi][ni], 0, 0, 0);
    }
    __syncthreads();
  }

  const int lr = (lane >> 4) * 4, lc = lane & 15;
  if (EPI == 0 || EPI == 1){
    u16* C = (u16*)Cout + (size_t)z * cBatch;
    #pragma unroll
    for (int mi = 0; mi < 4; mi++){
      #pragma unroll
      for (int ni = 0; ni < 4; ni++){
        int col = n0 + wn + ni * 16 + lc;
        float bv = (EPI == 0) ? bias[col] : 0.f;
        #pragma unroll
        for (int r = 0; r < 4; r++){
          int row = m0 + wm + mi * 16 + lr + r;
          C[(size_t)row * ldc + col] = f2bf(acc[mi][ni][r] * scale + bv);
        }
      }
    }
  } else if (EPI == 3){
    u16* C = (u16*)Cout;
    #pragma unroll
    for (int mi = 0; mi < 4; mi++){
      int rowb = m0 + wm + mi * 16 + lr;
      int b    = rowb >> 11;
      int rloc = rowb & 2047;
      #pragma unroll
      for (int ni = 0; ni < 4; ni++){
        int col = n0 + wn + ni * 16 + lc;
        float bv = bias[col];
        u32 pk[2];
        pk[0] = (u32)f2bf(acc[mi][ni][0] + bv) | ((u32)f2bf(acc[mi][ni][1] + bv) << 16);
        pk[1] = (u32)f2bf(acc[mi][ni][2] + bv) | ((u32)f2bf(acc[mi][ni][3] + bv) << 16);
        *(uint2*)&C[(size_t)b * (1024ull * 2048) + (size_t)col * 2048 + rloc] =
            make_uint2(pk[0], pk[1]);
      }
    }
  } else {
    float* C = (float*)Cout;
    #pragma unroll
    for (int mi = 0; mi < 4; mi++){
      #pragma unroll
      for (int ni = 0; ni < 4; ni++){
        int col = n0 + wn + ni * 16 + lc;
        float bv = bias[col];
        #pragma unroll
        for (int r = 0; r < 4; r++){
          int row = m0 + wm + mi * 16 + lr + r;
          float g  = acc[mi][ni][r] + bv;
          float sg = 1.f / (1.f + __expf(-g));
          float xv = bf2f(xg[(size_t)row * 1024 + col]);
          C[(size_t)row * ldc + col] =
              xv * maskp[row] * sg + q0p[(size_t)row * 1024 + col];
        }
      }
    }
  }
}

// ---------------------------------------------------------------------------
// B=8, L=2048, D=1024. All inputs fp32. Pipeline (bigws):
//   1. Wq/Wk/Wv/Wg -> bf16 transposed ([N][K]) in ws
//   2. projections read fp32 q/k/v DIRECTLY (AMODE=0 reg-staged, no cvt pass);
//      V proj stores TRANSPOSED -> vpT [b][d][l]
//   3. per chunk: S = qp kp^T /32 ; softmax ; x = P V
//   4. gate GEMM over concat(qp,x) with fused sigmoid/mask/residual epilogue
// ---------------------------------------------------------------------------
extern "C" void kernel_launch(void* const* d_in, const int* in_sizes, int n_in,
                              void* d_out, int out_size, void* d_ws, size_t ws_size,
                              hipStream_t stream)
{
  const float* q    = (const float*)d_in[0];
  const float* k    = (const float*)d_in[1];
  const float* v    = (const float*)d_in[2];
  const float* mask = (const float*)d_in[3];
  const float* Wq   = (const float*)d_in[4];
  const float* bq   = (const float*)d_in[5];
  const float* Wk   = (const float*)d_in[6];
  const float* bk   = (const float*)d_in[7];
  const float* Wv   = (const float*)d_in[8];
  const float* bv   = (const float*)d_in[9];
  const float* Wg   = (const float*)d_in[10];
  const float* bg   = (const float*)d_in[11];
  float* out = (float*)d_out;

  char* ws = (char*)d_ws;
  const size_t MB = 1024ull * 1024ull;
  u16* WqT = (u16*)(ws + 0 * MB);    // [1024][1024] bf16
  u16* WkT = (u16*)(ws + 2 * MB);
  u16* WvT = (u16*)(ws + 4 * MB);
  u16* WgT = (u16*)(ws + 6 * MB);    // [1024][2048] bf16
  u16* qp  = (u16*)(ws + 10 * MB);   // [16384][1024] bf16
  u16* kp  = (u16*)(ws + 42 * MB);   // [16384][1024] bf16 ; x overlays per batch
  u16* vpT = (u16*)(ws + 74 * MB);   // [8][1024][2048] bf16 (V proj, transposed)
  u16* S   = (u16*)(ws + 106 * MB);  // [nb][2048][2048] bf16, reused per chunk
  u16* x   = kp;

  const bool bigws = ws_size >= 138 * MB;
  int nb = 8;
  while (nb > 1 && 106 * MB + (size_t)nb * 8 * MB > ws_size) nb >>= 1;
  const int nchunks = 8 / nb;

  dim3 B(256);
  dim3 T5(512);

  // 1. weights -> bf16, transposed to [N][K]
  transpose_w_bf16<<<dim3(16, 16, 1), B, 0, stream>>>(Wq, WqT, 1024, 1024);
  transpose_w_bf16<<<dim3(16, 16, 1), B, 0, stream>>>(Wk, WkT, 1024, 1024);
  transpose_w_bf16<<<dim3(16, 16, 1), B, 0, stream>>>(Wv, WvT, 1024, 1024);
  transpose_w_bf16<<<dim3(32, 16, 1), B, 0, stream>>>(Wg, WgT, 2048, 1024);

  if (bigws){
    // 2. projections: [16384,1024] x [1024,1024], fp32 A direct (no cvt pass)
    gemm256<0, 0><<<dim3(4, 64, 1), T5, 0, stream>>>(q, nullptr, nullptr, WqT,
        1024, 1024, 1024, qp, 1024, bq, 1.f, 0, 0, 0, nullptr, nullptr, nullptr);
    gemm256<0, 0><<<dim3(4, 64, 1), T5, 0, stream>>>(k, nullptr, nullptr, WkT,
        1024, 1024, 1024, kp, 1024, bk, 1.f, 0, 0, 0, nullptr, nullptr, nullptr);
    gemm256<0, 3><<<dim3(4, 64, 1), T5, 0, stream>>>(v, nullptr, nullptr, WvT,
        1024, 1024, 1024, vpT, 0, bv, 1.f, 0, 0, 0, nullptr, nullptr, nullptr);

    // 3. attention middle, nb batches at a time
    for (int c = 0; c < nchunks; c++){
      const size_t boff = (size_t)c * nb;
      gemm256<1, 1><<<dim3(8, 8, nb), T5, 0, stream>>>(nullptr,
          qp + boff * 2048 * 1024, nullptr, kp + boff * 2048 * 1024,
          1024, 1024, 1024, S, 2048, nullptr, 0.03125f,
          2048ull * 1024, 2048ull * 1024, 2048ull * 2048, nullptr, nullptr, nullptr);
      softmax_rows<<<dim3(nb * 512, 1, 1), B, 0, stream>>>(S);
      gemm256<1, 1><<<dim3(4, 8, nb), T5, 0, stream>>>(nullptr,
          S, nullptr, vpT + boff * 1024 * 2048,
          2048, 2048, 2048, x + boff * 2048 * 1024, 1024, nullptr, 1.f,
          2048ull * 2048, 1024ull * 2048, 2048ull * 1024, nullptr, nullptr, nullptr);
    }

    // 4. gate GEMM over concat(qp, x) + fused epilogue -> fp32 out
    gemm256<2, 2><<<dim3(4, 64, 1), T5, 0, stream>>>(nullptr, qp, x, WgT,
        1024, 2048, 2048, out, 1024, bg, 1.f, 0, 0, 0, x, mask, q);
  } else {
    // fallback: original 128^2 pipeline with fp32 staging projections
    gemm128<0, 0><<<dim3(8, 128, 1), B, 0, stream>>>(q, nullptr, nullptr, WqT,
        1024, 1024, 1024, qp, 1024, bq, 1.f, 0, 0, 0, nullptr, nullptr, nullptr);
    gemm128<0, 0><<<dim3(8, 128, 1), B, 0, stream>>>(k, nullptr, nullptr, WkT,
        1024, 1024, 1024, kp, 1024, bk, 1.f, 0, 0, 0, nullptr, nullptr, nullptr);
    gemm128<0, 3><<<dim3(8, 128, 1), B, 0, stream>>>(v, nullptr, nullptr, WvT,
        1024, 1024, 1024, vpT, 0, bv, 1.f, 0, 0, 0, nullptr, nullptr, nullptr);

    for (int c = 0; c < nchunks; c++){
      const size_t boff = (size_t)c * nb;
      gemm128<1, 1><<<dim3(16, 16, nb), B, 0, stream>>>(nullptr,
          qp + boff * 2048 * 1024, nullptr, kp + boff * 2048 * 1024,
          1024, 1024, 1024, S, 2048, nullptr, 0.03125f,
          2048ull * 1024, 2048ull * 1024, 2048ull * 2048, nullptr, nullptr, nullptr);
      softmax_rows<<<dim3(nb * 512, 1, 1), B, 0, stream>>>(S);
      gemm128<1, 1><<<dim3(8, 16, nb), B, 0, stream>>>(nullptr,
          S, nullptr, vpT + boff * 1024 * 2048,
          2048, 2048, 2048, x + boff * 2048 * 1024, 1024, nullptr, 1.f,
          2048ull * 2048, 1024ull * 2048, 2048ull * 1024, nullptr, nullptr, nullptr);
    }

    gemm128<2, 2><<<dim3(8, 128, 1), B, 0, stream>>>(nullptr, qp, x, WgT,
        1024, 2048, 2048, out, 1024, bg, 1.f, 0, 0, 0, x, mask, q);
  }
}

// Round 4
// 625.711 us; speedup vs baseline: 1.0587x; 1.0587x over previous
//
#include <hip/hip_runtime.h>

typedef unsigned int u32;
typedef unsigned short u16;
using v4f    = __attribute__((ext_vector_type(4))) float;
using short8 = __attribute__((ext_vector_type(8))) short;

#define GAS __attribute__((address_space(1)))
#define LAS __attribute__((address_space(3)))

// ---- bf16 helpers (RNE, matches HW convert; inputs are finite) ----
__device__ __forceinline__ u16 f2bf(float f){
  u32 u = __builtin_bit_cast(u32, f);
  u32 r = (u + 0x7fffu + ((u >> 16) & 1u)) >> 16;
  return (u16)r;
}
__device__ __forceinline__ float bf2f(u16 h){
  u32 u = ((u32)h) << 16;
  return __builtin_bit_cast(float, u);
}

// async global->LDS, 16B per lane. LDS dest must be wave-uniform base + lane*16.
__device__ __forceinline__ void gld_lds16(const void* g, void* l){
  __builtin_amdgcn_global_load_lds((const GAS u32*)g, (LAS u32*)l, 16, 0, 0);
}

// ---- transpose fp32 [K][N] -> bf16 [N][K] (weights only) ----
__global__ __launch_bounds__(256) void transpose_w_bf16(
    const float* __restrict__ in, u16* __restrict__ out, int K, int N)
{
  __shared__ float t[64][65];
  const int k0 = blockIdx.x * 64, n0 = blockIdx.y * 64;
  const int tx = threadIdx.x & 63, ty = threadIdx.x >> 6;
  #pragma unroll
  for (int i = 0; i < 16; i++){
    int r = ty + i * 4;
    t[r][tx] = in[(size_t)(k0 + r) * N + (n0 + tx)];
  }
  __syncthreads();
  #pragma unroll
  for (int i = 0; i < 16; i++){
    int r = ty + i * 4;
    out[(size_t)(n0 + r) * K + (k0 + tx)] = f2bf(t[tx][r]);
  }
}

// ---- in-place softmax, one WAVE per 2048-elem row (4 rows/block) ----
__global__ __launch_bounds__(256) void softmax_rows(u16* __restrict__ S){
  const int lane = threadIdx.x & 63, wid = threadIdx.x >> 6;
  u16* p = S + ((size_t)blockIdx.x * 4 + wid) * 2048;
  uint4 u[4];
  #pragma unroll
  for (int j = 0; j < 4; j++) u[j] = ((const uint4*)p)[lane + j * 64];
  float f[32];
  #pragma unroll
  for (int j = 0; j < 4; j++){
    u32 w4[4] = {u[j].x, u[j].y, u[j].z, u[j].w};
    #pragma unroll
    for (int i = 0; i < 4; i++){
      f[j * 8 + 2*i]     = bf2f((u16)(w4[i] & 0xffffu));
      f[j * 8 + 2*i + 1] = bf2f((u16)(w4[i] >> 16));
    }
  }
  float m = f[0];
  #pragma unroll
  for (int i = 1; i < 32; i++) m = fmaxf(m, f[i]);
  #pragma unroll
  for (int o = 32; o >= 1; o >>= 1) m = fmaxf(m, __shfl_xor(m, o));
  float s = 0.f;
  #pragma unroll
  for (int i = 0; i < 32; i++){ f[i] = __expf(f[i] - m); s += f[i]; }
  #pragma unroll
  for (int o = 32; o >= 1; o >>= 1) s += __shfl_xor(s, o);
  const float inv = 1.f / s;
  #pragma unroll
  for (int j = 0; j < 4; j++){
    u32 w4[4];
    #pragma unroll
    for (int i = 0; i < 4; i++)
      w4[i] = (u32)f2bf(f[j * 8 + 2*i] * inv) |
              ((u32)f2bf(f[j * 8 + 2*i + 1] * inv) << 16);
    ((uint4*)p)[lane + j * 64] = make_uint4(w4[0], w4[1], w4[2], w4[3]);
  }
}

// ===========================================================================
// 256x256x64 bf16 GEMM, free-flow register-pipelined K-loop (round-2 body,
//   measured best) with ONE barrier per K-tile:
//     top:  lgkmcnt(0) + vmcnt(0)  [drain ops issued a FULL tile ago]
//           s_barrier               [all waves: tile data landed, WAR safe]
//     then: issue next tile's staging; free-flow ds_read/MFMA pipeline.
//   Wait-before-barrier is the valid single-barrier form: each wave's own
//   drain completes BEFORE the sync point, so after the barrier every wave
//   knows ALL waves' staged data landed.
//   512 threads = 8 waves (2M x 4N), per-wave output 128x64. 128 KiB LDS dbuf.
// LDS swizzle: linear dest; slot (r,c8) holds global k-chunk (c8 ^ (r&7));
//   reads apply the same XOR. (bank-conflict = 0, verified r1-r3)
// AMODE: 0 = A fp32 global, reg-staged (load early / cvt+ds_write late, T14)
//        1 = A bf16 via global_load_lds
//        2 = A concat(qp,x) bf16 (K split at 1024, wave-uniform select)
// EPI:   0 = +bias, bf16   1 = *scale, bf16   2 = gate-fused, fp32
//        3 = +bias, bf16 TRANSPOSED [batch][col][rowlocal]
// ===========================================================================
#define MFMA8(B0, B1, N0, N1)                                               \
    __builtin_amdgcn_s_setprio(1);                                          \
    _Pragma("unroll")                                                       \
    for (int mi = 0; mi < 8; mi++){                                         \
      acc[mi][N0] = __builtin_amdgcn_mfma_f32_16x16x32_bf16(                \
                      a[mi], (B0), acc[mi][N0], 0, 0, 0);                   \
      acc[mi][N1] = __builtin_amdgcn_mfma_f32_16x16x32_bf16(                \
                      a[mi], (B1), acc[mi][N1], 0, 0, 0);                   \
    }                                                                       \
    __builtin_amdgcn_s_setprio(0);

template<int AMODE, int EPI>
__global__ __launch_bounds__(512) void gemm256(
    const float* __restrict__ Af,
    const u16* __restrict__ Ab,
    const u16* __restrict__ A2b,
    const u16* __restrict__ BT,
    int lda, int ldb, int K,
    void* __restrict__ Cout, int ldc,
    const float* __restrict__ bias, float scale,
    size_t aBatch, size_t bBatch, size_t cBatch,
    const u16* __restrict__ xg,
    const float* __restrict__ maskp,
    const float* __restrict__ q0p)
{
  constexpr int BK = 64;
  __shared__ __align__(16) u16 As[2][2][128 * 64];   // [buf][half][r*64 + c8*8 + e]
  __shared__ __align__(16) u16 Bs[2][2][128 * 64];

  const int z   = blockIdx.z;
  // GROUP-8 swizzle: 8 consecutive lin blocks share a B-panel, walk 8 A-panels
  const int gx   = (int)gridDim.x;
  const int lin  = (int)blockIdx.y * gx + (int)blockIdx.x;
  const int l2gx = 31 - __clz(gx);
  const int g    = lin >> (3 + l2gx);
  const int rem  = lin & ((gx << 3) - 1);
  const int m0   = ((g << 3) + (rem & 7)) * 256;
  const int n0   = (rem >> 3) * 256;

  const int tid  = (int)threadIdx.x;
  const int lane = tid & 63, wid = tid >> 6;
  const int wm   = (wid >> 2) * 128;     // A half = wid>>2
  const int wn   = (wid & 3) * 64;
  const int wnh  = wn >> 7;              // B half
  const int wnl  = wn & 127;

  const u16* Az = Ab + (size_t)z * aBatch;
  const u16* Bz = BT + (size_t)z * bBatch;

  // staging geometry: load i covers rows (tid+i*512)>>3 of a 128x64 half.
  // slot (r,c8) <- global chunk (c8 ^ (r&7))   [inverse swizzle on source]
  u32 offA[2][2], offB[2][2], ldsOff[2];
  #pragma unroll
  for (int i = 0; i < 2; i++){
    int idx = tid + i * 512;
    int r = idx >> 3, c8 = idx & 7;
    int c8s = c8 ^ (r & 7);
    #pragma unroll
    for (int h = 0; h < 2; h++){
      offA[h][i] = (u32)(((m0 + h * 128 + r) * lda + c8s * 8) * 2);
      offB[h][i] = (u32)(((n0 + h * 128 + r) * ldb + c8s * 8) * 2);
    }
    ldsOff[i] = (u32)(idx * 16);
  }

  // stage tile kt into dbuf: B always via DMA; A via DMA only for AMODE!=0
  auto stage = [&](int kt, int dbuf){
    const u32 kb = (u32)(kt * BK * 2);
    if (AMODE != 0){
      const u16* Asrc; u32 ka;
      if (AMODE == 2){
        Asrc = (kt * BK < 1024) ? Az : A2b;
        ka = (u32)(((kt * BK) & 1023) * 2);
      } else {
        Asrc = Az;
        ka = (u32)(kt * BK * 2);
      }
      #pragma unroll
      for (int h = 0; h < 2; h++)
        #pragma unroll
        for (int i = 0; i < 2; i++)
          gld_lds16((const char*)Asrc + offA[h][i] + ka,
                    (char*)&As[dbuf][h][0] + ldsOff[i]);
    }
    #pragma unroll
    for (int h = 0; h < 2; h++)
      #pragma unroll
      for (int i = 0; i < 2; i++)
        gld_lds16((const char*)Bz + offB[h][i] + kb,
                  (char*)&Bs[dbuf][h][0] + ldsOff[i]);
  };

  // AMODE==0: fp32 A reg-staging (T14 split: load early, cvt+ds_write late)
  v4f afr[2][2][2];
  auto loadA = [&](int kt){
    if (AMODE != 0) return;
    #pragma unroll
    for (int h = 0; h < 2; h++)
      #pragma unroll
      for (int i = 0; i < 2; i++){
        int idx = tid + i * 512;
        int r = idx >> 3, c8s = (idx & 7) ^ (r & 7);
        const float* src = Af + (size_t)(m0 + h * 128 + r) * lda + kt * BK + c8s * 8;
        afr[h][i][0] = ((const v4f*)src)[0];
        afr[h][i][1] = ((const v4f*)src)[1];
      }
  };
  auto writeA = [&](int dbuf){
    if (AMODE != 0) return;
    #pragma unroll
    for (int h = 0; h < 2; h++)
      #pragma unroll
      for (int i = 0; i < 2; i++){
        int idx = tid + i * 512;
        u32 q0 = (u32)f2bf(afr[h][i][0].x) | ((u32)f2bf(afr[h][i][0].y) << 16);
        u32 q1 = (u32)f2bf(afr[h][i][0].z) | ((u32)f2bf(afr[h][i][0].w) << 16);
        u32 q2 = (u32)f2bf(afr[h][i][1].x) | ((u32)f2bf(afr[h][i][1].y) << 16);
        u32 q3 = (u32)f2bf(afr[h][i][1].z) | ((u32)f2bf(afr[h][i][1].w) << 16);
        *(uint4*)((char*)&As[dbuf][h][0] + idx * 16) = make_uint4(q0, q1, q2, q3);
      }
  };

  v4f acc[8][4];
  #pragma unroll
  for (int mi = 0; mi < 8; mi++)
    #pragma unroll
    for (int ni = 0; ni < 4; ni++)
      acc[mi][ni] = (v4f){0.f, 0.f, 0.f, 0.f};

  // read-side swizzle: per-lane constant chunk offsets (elements)
  const int ll  = lane & 15, lq = lane >> 4;
  const int ch0 = ((0 + lq) ^ (ll & 7)) << 3;   // k 0..31
  const int ch4 = ((4 + lq) ^ (ll & 7)) << 3;   // k 32..63

  // ---- prologue: stage tile 0 into buf 0
  if (AMODE == 0){
    loadA(0);
    stage(0, 0);        // B via DMA
    writeA(0);          // compiler waits the fp32 loads here
  } else {
    stage(0, 0);
  }

  const int nt = K / BK;
  for (int kt = 0; kt < nt; kt++){
    const int buf = kt & 1;
    const bool pf = (kt + 1 < nt);

    // ---- single tile-top sync: drain ops issued a FULL tile ago, then BAR.
    asm volatile("s_waitcnt lgkmcnt(0)" ::: "memory");
    asm volatile("s_waitcnt vmcnt(0)" ::: "memory");
    __builtin_amdgcn_s_barrier();
    asm volatile("" ::: "memory");

    // ---- issue next tile's staging (gets a full tile of flight time)
    if (pf){
      if (AMODE == 0) loadA(kt + 1);
      stage(kt + 1, buf ^ 1);
    }

    const u16* aB = &As[buf][wid >> 2][0] + ll * 64;
    const u16* bB = &Bs[buf][wnh][0] + (wnl + ll) * 64;

    short8 a[8], b0[2], b1[2], p0[2], p1[2];
    // R0: k 0..31 fragments for M0
    b0[0] = *(const short8*)(bB + ch0);
    b0[1] = *(const short8*)(bB + ch0 + 1024);
    #pragma unroll
    for (int mi = 0; mi < 8; mi++) a[mi] = *(const short8*)(aB + ch0 + mi * 1024);
    // R1: b-frags for M1 (fly under M0)
    b1[0] = *(const short8*)(bB + ch0 + 2048);
    b1[1] = *(const short8*)(bB + ch0 + 3072);
    // M0: k 0..31, ni 0..1
    MFMA8(b0[0], b0[1], 0, 1)
    // R2: b-frags for M2 (fly under M1)
    p0[0] = *(const short8*)(bB + ch4);
    p0[1] = *(const short8*)(bB + ch4 + 1024);
    // M1: k 0..31, ni 2..3
    MFMA8(b1[0], b1[1], 2, 3)
    // R3: b-frags for M3 + a-reload (in place, after last use of a@k0).
    p1[0] = *(const short8*)(bB + ch4 + 2048);
    p1[1] = *(const short8*)(bB + ch4 + 3072);
    __builtin_amdgcn_sched_barrier(0);   // cap VGPR: no a-reload hoist above M1
    #pragma unroll
    for (int mi = 0; mi < 8; mi++) a[mi] = *(const short8*)(aB + ch4 + mi * 1024);
    // M2: k 32..63, ni 0..1
    MFMA8(p0[0], p0[1], 0, 1)
    // M3: k 32..63, ni 2..3
    MFMA8(p1[0], p1[1], 2, 3)

    if (pf) writeA(buf ^ 1);             // fp32 A cvt + ds_write late (AMODE==0)
  }

  // epilogue: C/D layout col = lane&15, row = (lane>>4)*4 + r (m89/m91)
  const int lr = lq * 4, lc = ll;
  if (EPI == 0 || EPI == 1){
    u16* C = (u16*)Cout + (size_t)z * cBatch;
    #pragma unroll
    for (int mi = 0; mi < 8; mi++){
      #pragma unroll
      for (int ni = 0; ni < 4; ni++){
        int col = n0 + wn + ni * 16 + lc;
        float bv = (EPI == 0) ? bias[col] : 0.f;
        #pragma unroll
        for (int r = 0; r < 4; r++){
          int row = m0 + wm + mi * 16 + lr + r;
          C[(size_t)row * ldc + col] = f2bf(acc[mi][ni][r] * scale + bv);
        }
      }
    }
  } else if (EPI == 3){
    u16* C = (u16*)Cout;
    #pragma unroll
    for (int mi = 0; mi < 8; mi++){
      int rowb = m0 + wm + mi * 16 + lr;        // multiple of 4, single batch
      int bb   = rowb >> 11;
      int rloc = rowb & 2047;
      #pragma unroll
      for (int ni = 0; ni < 4; ni++){
        int col = n0 + wn + ni * 16 + lc;
        float bv = bias[col];
        u32 pk0 = (u32)f2bf(acc[mi][ni][0] + bv) | ((u32)f2bf(acc[mi][ni][1] + bv) << 16);
        u32 pk1 = (u32)f2bf(acc[mi][ni][2] + bv) | ((u32)f2bf(acc[mi][ni][3] + bv) << 16);
        *(uint2*)&C[(size_t)bb * (1024ull * 2048) + (size_t)col * 2048 + rloc] =
            make_uint2(pk0, pk1);
      }
    }
  } else {
    float* C = (float*)Cout;
    #pragma unroll
    for (int mi = 0; mi < 8; mi++){
      #pragma unroll
      for (int ni = 0; ni < 4; ni++){
        int col = n0 + wn + ni * 16 + lc;
        float bv = bias[col];
        #pragma unroll
        for (int r = 0; r < 4; r++){
          int row = m0 + wm + mi * 16 + lr + r;
          float gg = acc[mi][ni][r] + bv;
          float sg = 1.f / (1.f + __expf(-gg));
          float xv = bf2f(xg[(size_t)row * 1024 + col]);
          C[(size_t)row * ldc + col] =
              xv * maskp[row] * sg + q0p[(size_t)row * 1024 + col];
        }
      }
    }
  }
}
#undef MFMA8

// ---- 128x128x64 kernel kept for the small-workspace fallback path ----
template<int AMODE, int EPI>
__global__ __launch_bounds__(256) void gemm128(
    const float* __restrict__ Af,
    const u16* __restrict__ Ab,
    const u16* __restrict__ A2b,
    const u16* __restrict__ BT,
    int lda, int ldb, int K,
    void* __restrict__ Cout, int ldc,
    const float* __restrict__ bias, float scale,
    size_t aBatch, size_t bBatch, size_t cBatch,
    const u16* __restrict__ xg,
    const float* __restrict__ maskp,
    const float* __restrict__ q0p)
{
  constexpr int BM = 128, BN = 128, BK = 64;
  __shared__ __align__(16) u16 As[BM * BK];
  __shared__ __align__(16) u16 Bs[BN * BK];
  const int z   = blockIdx.z;
  const int lin  = blockIdx.y * gridDim.x + blockIdx.x;
  const int l2gx = 31 - __clz((int)gridDim.x);
  const int g    = lin >> (3 + l2gx);
  const int rem  = lin & (((int)gridDim.x << 3) - 1);
  const int m0   = ((g << 3) + (rem & 7)) * BM;
  const int n0   = (rem >> 3) * BN;
  const int tid = threadIdx.x;
  const int lane = tid & 63, wid = tid >> 6;
  const int wm = (wid >> 1) * 64, wn = (wid & 1) * 64;
  const u16* Abz = Ab + (size_t)z * aBatch;
  const u16* BTz = BT + (size_t)z * bBatch;

  v4f acc[4][4];
  #pragma unroll
  for (int mi = 0; mi < 4; mi++)
    #pragma unroll
    for (int ni = 0; ni < 4; ni++)
      acc[mi][ni] = (v4f){0.f, 0.f, 0.f, 0.f};

  for (int k0 = 0; k0 < K; k0 += BK){
    if (AMODE == 0){
      #pragma unroll
      for (int i = 0; i < 4; i++){
        int idx = tid + i * 256;
        int r = idx >> 3, s = idx & 7;
        const float* src = Af + (size_t)(m0 + r) * lda + (k0 + s * 8);
        v4f lo = ((const v4f*)src)[0];
        v4f hi = ((const v4f*)src)[1];
        u32 p0 = (u32)f2bf(lo.x) | ((u32)f2bf(lo.y) << 16);
        u32 p1 = (u32)f2bf(lo.z) | ((u32)f2bf(lo.w) << 16);
        u32 p2 = (u32)f2bf(hi.x) | ((u32)f2bf(hi.y) << 16);
        u32 p3 = (u32)f2bf(hi.z) | ((u32)f2bf(hi.w) << 16);
        *(uint4*)&As[(size_t)idx * 8] = make_uint4(p0, p1, p2, p3);
      }
    } else {
      #pragma unroll
      for (int i = 0; i < 4; i++){
        int idx = tid + i * 256;
        int r = idx >> 3, s = idx & 7;
        int kk = k0 + s * 8;
        const u16* src;
        if (AMODE == 2){
          src = (kk < 1024) ? (Abz + (size_t)(m0 + r) * 1024 + kk)
                            : (A2b + (size_t)(m0 + r) * 1024 + (kk - 1024));
        } else {
          src = Abz + (size_t)(m0 + r) * lda + kk;
        }
        gld_lds16(src, &As[(size_t)idx * 8]);
      }
    }
    #pragma unroll
    for (int i = 0; i < 4; i++){
      int idx = tid + i * 256;
      int r = idx >> 3, s = idx & 7;
      gld_lds16(BTz + (size_t)(n0 + r) * ldb + (k0 + s * 8), &Bs[(size_t)idx * 8]);
    }
    __syncthreads();
    #pragma unroll
    for (int ks = 0; ks < BK; ks += 32){
      short8 a[4], b[4];
      #pragma unroll
      for (int mi = 0; mi < 4; mi++)
        a[mi] = *(const short8*)&As[(wm + mi * 16 + (lane & 15)) * BK + ks + (lane >> 4) * 8];
      #pragma unroll
      for (int ni = 0; ni < 4; ni++)
        b[ni] = *(const short8*)&Bs[(wn + ni * 16 + (lane & 15)) * BK + ks + (lane >> 4) * 8];
      #pragma unroll
      for (int mi = 0; mi < 4; mi++)
        #pragma unroll
        for (int ni = 0; ni < 4; ni++)
          acc[mi][ni] = __builtin_amdgcn_mfma_f32_16x16x32_bf16(a[mi], b[ni], acc[mi][ni], 0, 0, 0);
    }
    __syncthreads();
  }

  const int lr = (lane >> 4) * 4, lc = lane & 15;
  if (EPI == 0 || EPI == 1){
    u16* C = (u16*)Cout + (size_t)z * cBatch;
    #pragma unroll
    for (int mi = 0; mi < 4; mi++){
      #pragma unroll
      for (int ni = 0; ni < 4; ni++){
        int col = n0 + wn + ni * 16 + lc;
        float bv = (EPI == 0) ? bias[col] : 0.f;
        #pragma unroll
        for (int r = 0; r < 4; r++){
          int row = m0 + wm + mi * 16 + lr + r;
          C[(size_t)row * ldc + col] = f2bf(acc[mi][ni][r] * scale + bv);
        }
      }
    }
  } else if (EPI == 3){
    u16* C = (u16*)Cout;
    #pragma unroll
    for (int mi = 0; mi < 4; mi++){
      int rowb = m0 + wm + mi * 16 + lr;
      int b    = rowb >> 11;
      int rloc = rowb & 2047;
      #pragma unroll
      for (int ni = 0; ni < 4; ni++){
        int col = n0 + wn + ni * 16 + lc;
        float bv = bias[col];
        u32 pk[2];
        pk[0] = (u32)f2bf(acc[mi][ni][0] + bv) | ((u32)f2bf(acc[mi][ni][1] + bv) << 16);
        pk[1] = (u32)f2bf(acc[mi][ni][2] + bv) | ((u32)f2bf(acc[mi][ni][3] + bv) << 16);
        *(uint2*)&C[(size_t)b * (1024ull * 2048) + (size_t)col * 2048 + rloc] =
            make_uint2(pk[0], pk[1]);
      }
    }
  } else {
    float* C = (float*)Cout;
    #pragma unroll
    for (int mi = 0; mi < 4; mi++){
      #pragma unroll
      for (int ni = 0; ni < 4; ni++){
        int col = n0 + wn + ni * 16 + lc;
        float bv = bias[col];
        #pragma unroll
        for (int r = 0; r < 4; r++){
          int row = m0 + wm + mi * 16 + lr + r;
          float g  = acc[mi][ni][r] + bv;
          float sg = 1.f / (1.f + __expf(-g));
          float xv = bf2f(xg[(size_t)row * 1024 + col]);
          C[(size_t)row * ldc + col] =
              xv * maskp[row] * sg + q0p[(size_t)row * 1024 + col];
        }
      }
    }
  }
}

// ---------------------------------------------------------------------------
// B=8, L=2048, D=1024. All inputs fp32. Pipeline (bigws):
//   1. Wq/Wk/Wv/Wg -> bf16 transposed ([N][K]) in ws
//   2. projections read fp32 q/k/v DIRECTLY (AMODE=0 reg-staged, no cvt pass);
//      V proj stores TRANSPOSED -> vpT [b][d][l]
//   3. per chunk: S = qp kp^T /32 ; softmax ; x = P V
//   4. gate GEMM over concat(qp,x) with fused sigmoid/mask/residual epilogue
// ---------------------------------------------------------------------------
extern "C" void kernel_launch(void* const* d_in, const int* in_sizes, int n_in,
                              void* d_out, int out_size, void* d_ws, size_t ws_size,
                              hipStream_t stream)
{
  const float* q    = (const float*)d_in[0];
  const float* k    = (const float*)d_in[1];
  const float* v    = (const float*)d_in[2];
  const float* mask = (const float*)d_in[3];
  const float* Wq   = (const float*)d_in[4];
  const float* bq   = (const float*)d_in[5];
  const float* Wk   = (const float*)d_in[6];
  const float* bk   = (const float*)d_in[7];
  const float* Wv   = (const float*)d_in[8];
  const float* bv   = (const float*)d_in[9];
  const float* Wg   = (const float*)d_in[10];
  const float* bg   = (const float*)d_in[11];
  float* out = (float*)d_out;

  char* ws = (char*)d_ws;
  const size_t MB = 1024ull * 1024ull;
  u16* WqT = (u16*)(ws + 0 * MB);    // [1024][1024] bf16
  u16* WkT = (u16*)(ws + 2 * MB);
  u16* WvT = (u16*)(ws + 4 * MB);
  u16* WgT = (u16*)(ws + 6 * MB);    // [1024][2048] bf16
  u16* qp  = (u16*)(ws + 10 * MB);   // [16384][1024] bf16
  u16* kp  = (u16*)(ws + 42 * MB);   // [16384][1024] bf16 ; x overlays per batch
  u16* vpT = (u16*)(ws + 74 * MB);   // [8][1024][2048] bf16 (V proj, transposed)
  u16* S   = (u16*)(ws + 106 * MB);  // [nb][2048][2048] bf16, reused per chunk
  u16* x   = kp;

  const bool bigws = ws_size >= 138 * MB;
  int nb = 8;
  while (nb > 1 && 106 * MB + (size_t)nb * 8 * MB > ws_size) nb >>= 1;
  const int nchunks = 8 / nb;

  dim3 B(256);
  dim3 T5(512);

  // 1. weights -> bf16, transposed to [N][K]
  transpose_w_bf16<<<dim3(16, 16, 1), B, 0, stream>>>(Wq, WqT, 1024, 1024);
  transpose_w_bf16<<<dim3(16, 16, 1), B, 0, stream>>>(Wk, WkT, 1024, 1024);
  transpose_w_bf16<<<dim3(16, 16, 1), B, 0, stream>>>(Wv, WvT, 1024, 1024);
  transpose_w_bf16<<<dim3(32, 16, 1), B, 0, stream>>>(Wg, WgT, 2048, 1024);

  if (bigws){
    // 2. projections: [16384,1024] x [1024,1024], fp32 A direct (no cvt pass)
    gemm256<0, 0><<<dim3(4, 64, 1), T5, 0, stream>>>(q, nullptr, nullptr, WqT,
        1024, 1024, 1024, qp, 1024, bq, 1.f, 0, 0, 0, nullptr, nullptr, nullptr);
    gemm256<0, 0><<<dim3(4, 64, 1), T5, 0, stream>>>(k, nullptr, nullptr, WkT,
        1024, 1024, 1024, kp, 1024, bk, 1.f, 0, 0, 0, nullptr, nullptr, nullptr);
    gemm256<0, 3><<<dim3(4, 64, 1), T5, 0, stream>>>(v, nullptr, nullptr, WvT,
        1024, 1024, 1024, vpT, 0, bv, 1.f, 0, 0, 0, nullptr, nullptr, nullptr);

    // 3. attention middle, nb batches at a time
    for (int c = 0; c < nchunks; c++){
      const size_t boff = (size_t)c * nb;
      gemm256<1, 1><<<dim3(8, 8, nb), T5, 0, stream>>>(nullptr,
          qp + boff * 2048 * 1024, nullptr, kp + boff * 2048 * 1024,
          1024, 1024, 1024, S, 2048, nullptr, 0.03125f,
          2048ull * 1024, 2048ull * 1024, 2048ull * 2048, nullptr, nullptr, nullptr);
      softmax_rows<<<dim3(nb * 512, 1, 1), B, 0, stream>>>(S);
      gemm256<1, 1><<<dim3(4, 8, nb), T5, 0, stream>>>(nullptr,
          S, nullptr, vpT + boff * 1024 * 2048,
          2048, 2048, 2048, x + boff * 2048 * 1024, 1024, nullptr, 1.f,
          2048ull * 2048, 1024ull * 2048, 2048ull * 1024, nullptr, nullptr, nullptr);
    }

    // 4. gate GEMM over concat(qp, x) + fused epilogue -> fp32 out
    gemm256<2, 2><<<dim3(4, 64, 1), T5, 0, stream>>>(nullptr, qp, x, WgT,
        1024, 2048, 2048, out, 1024, bg, 1.f, 0, 0, 0, x, mask, q);
  } else {
    // fallback: original 128^2 pipeline with fp32 staging projections
    gemm128<0, 0><<<dim3(8, 128, 1), B, 0, stream>>>(q, nullptr, nullptr, WqT,
        1024, 1024, 1024, qp, 1024, bq, 1.f, 0, 0, 0, nullptr, nullptr, nullptr);
    gemm128<0, 0><<<dim3(8, 128, 1), B, 0, stream>>>(k, nullptr, nullptr, WkT,
        1024, 1024, 1024, kp, 1024, bk, 1.f, 0, 0, 0, nullptr, nullptr, nullptr);
    gemm128<0, 3><<<dim3(8, 128, 1), B, 0, stream>>>(v, nullptr, nullptr, WvT,
        1024, 1024, 1024, vpT, 0, bv, 1.f, 0, 0, 0, nullptr, nullptr, nullptr);

    for (int c = 0; c < nchunks; c++){
      const size_t boff = (size_t)c * nb;
      gemm128<1, 1><<<dim3(16, 16, nb), B, 0, stream>>>(nullptr,
          qp + boff * 2048 * 1024, nullptr, kp + boff * 2048 * 1024,
          1024, 1024, 1024, S, 2048, nullptr, 0.03125f,
          2048ull * 1024, 2048ull * 1024, 2048ull * 2048, nullptr, nullptr, nullptr);
      softmax_rows<<<dim3(nb * 512, 1, 1), B, 0, stream>>>(S);
      gemm128<1, 1><<<dim3(8, 16, nb), B, 0, stream>>>(nullptr,
          S, nullptr, vpT + boff * 1024 * 2048,
          2048, 2048, 2048, x + boff * 2048 * 1024, 1024, nullptr, 1.f,
          2048ull * 2048, 1024ull * 2048, 2048ull * 1024, nullptr, nullptr, nullptr);
    }

    gemm128<2, 2><<<dim3(8, 128, 1), B, 0, stream>>>(nullptr, qp, x, WgT,
        1024, 2048, 2048, out, 1024, bg, 1.f, 0, 0, 0, x, mask, q);
  }
}